// Round 1
// baseline (1538.424 us; speedup 1.0000x reference)
//
#include <hip/hip_runtime.h>

#define N_NODES 50000
#define N_EDGES 800000

// ---------------- degree count ----------------
__global__ void k_deg(const int* __restrict__ dst, float* __restrict__ cnt) {
    int e = blockIdx.x * blockDim.x + threadIdx.x;
    if (e < N_EDGES) unsafeAtomicAdd(&cnt[dst[e]], 1.0f);
}

// ---------------- edge scatter: sum[dst] += feat[src], 64 channels ----------------
// 16 threads per edge, each handles 4 contiguous channels via float4 gather.
__global__ void k_scatter64(const int* __restrict__ src, const int* __restrict__ dst,
                            const float* __restrict__ feat, float* __restrict__ sum) {
    unsigned t = blockIdx.x * blockDim.x + threadIdx.x;
    unsigned e = t >> 4;
    if (e >= N_EDGES) return;
    int cg = (int)(t & 15u) << 2;
    int s = src[e], d = dst[e];
    const float4 v = *(const float4*)(feat + (size_t)s * 64 + cg);
    float* o = sum + (size_t)d * 64 + cg;
    unsafeAtomicAdd(o + 0, v.x);
    unsafeAtomicAdd(o + 1, v.y);
    unsafeAtomicAdd(o + 2, v.z);
    unsafeAtomicAdd(o + 3, v.w);
}

// ---------------- layer1: h1 = relu(mean @ wl + x @ wr + b), 64 -> 64 ----------------
// block = 256 threads = 4 nodes x 64 output channels. Weights staged in LDS.
__global__ void k_layer1(const float* __restrict__ x, const float* __restrict__ sum,
                         const float* __restrict__ cnt,
                         const float* __restrict__ wl, const float* __restrict__ wr,
                         const float* __restrict__ b, float* __restrict__ h1) {
    __shared__ float swl[64 * 64];
    __shared__ float swr[64 * 64];
    __shared__ float sx[4][64];
    __shared__ float sm[4][64];
    for (int i = threadIdx.x; i < 64 * 64; i += 256) { swl[i] = wl[i]; swr[i] = wr[i]; }
    int ln = threadIdx.x >> 6;
    int c  = threadIdx.x & 63;
    int node = blockIdx.x * 4 + ln;           // N % 4 == 0, no partial blocks
    float inv = 1.0f / fmaxf(cnt[node], 1.0f);
    sx[ln][c] = x[(size_t)node * 64 + c];
    sm[ln][c] = sum[(size_t)node * 64 + c] * inv;
    __syncthreads();
    float acc = b[c];
#pragma unroll
    for (int k = 0; k < 64; ++k)
        acc = fmaf(sm[ln][k], swl[k * 64 + c], fmaf(sx[ln][k], swr[k * 64 + c], acc));
    h1[(size_t)node * 64 + c] = fmaxf(acc, 0.0f);
}

// ---------------- layer2: h2 = relu(mean @ wl + h1 @ wr + b), 64 -> 32 ----------------
// block = 256 threads = 8 nodes x 32 output channels.
__global__ void k_layer2(const float* __restrict__ h1, const float* __restrict__ sum,
                         const float* __restrict__ cnt,
                         const float* __restrict__ wl, const float* __restrict__ wr,
                         const float* __restrict__ b, float* __restrict__ h2) {
    __shared__ float swl[64 * 32];
    __shared__ float swr[64 * 32];
    __shared__ float sh[8][64];
    __shared__ float sm[8][64];
    for (int i = threadIdx.x; i < 64 * 32; i += 256) { swl[i] = wl[i]; swr[i] = wr[i]; }
    int ln = threadIdx.x >> 5;
    int c  = threadIdx.x & 31;
    int node = blockIdx.x * 8 + ln;           // N % 8 == 0, no partial blocks
    float inv = 1.0f / fmaxf(cnt[node], 1.0f);
    sh[ln][c]      = h1[(size_t)node * 64 + c];
    sh[ln][c + 32] = h1[(size_t)node * 64 + c + 32];
    sm[ln][c]      = sum[(size_t)node * 64 + c] * inv;
    sm[ln][c + 32] = sum[(size_t)node * 64 + c + 32] * inv;
    __syncthreads();
    float acc = b[c];
#pragma unroll
    for (int k = 0; k < 64; ++k)
        acc = fmaf(sm[ln][k], swl[k * 32 + c], fmaf(sh[ln][k], swr[k * 32 + c], acc));
    h2[(size_t)node * 32 + c] = fmaxf(acc, 0.0f);
}

// ---------------- classifier: out = relu(h2 @ wc1 + bc1) @ wc2 + bc2 ----------------
// one node per thread; tiny weights staged in LDS.
__global__ void k_classifier(const float* __restrict__ h2,
                             const float* __restrict__ wc1, const float* __restrict__ bc1,
                             const float* __restrict__ wc2, const float* __restrict__ bc2,
                             float* __restrict__ out) {
    __shared__ float s1[32 * 16];
    __shared__ float sb1[16];
    __shared__ float s2[16 * 2];
    __shared__ float sb2[2];
    int t = threadIdx.x;
    for (int i = t; i < 32 * 16; i += 256) s1[i] = wc1[i];
    if (t < 16) sb1[t] = bc1[t];
    if (t < 32) s2[t] = wc2[t];
    if (t < 2)  sb2[t] = bc2[t];
    __syncthreads();
    int node = blockIdx.x * 256 + t;
    if (node >= N_NODES) return;
    float h[32];
    const float4* hp = (const float4*)(h2 + (size_t)node * 32);
#pragma unroll
    for (int i = 0; i < 8; ++i) {
        float4 v = hp[i];
        h[i * 4 + 0] = v.x; h[i * 4 + 1] = v.y; h[i * 4 + 2] = v.z; h[i * 4 + 3] = v.w;
    }
    float o0 = sb2[0], o1 = sb2[1];
#pragma unroll
    for (int j = 0; j < 16; ++j) {
        float a = sb1[j];
#pragma unroll
        for (int k = 0; k < 32; ++k) a = fmaf(h[k], s1[k * 16 + j], a);
        a = fmaxf(a, 0.0f);
        o0 = fmaf(a, s2[j * 2 + 0], o0);
        o1 = fmaf(a, s2[j * 2 + 1], o1);
    }
    *(float2*)(out + (size_t)node * 2) = make_float2(o0, o1);
}

extern "C" void kernel_launch(void* const* d_in, const int* in_sizes, int n_in,
                              void* d_out, int out_size, void* d_ws, size_t ws_size,
                              hipStream_t stream) {
    const float* x   = (const float*)d_in[0];
    const int*   ei  = (const int*)d_in[1];
    const int*   src = ei;              // edge_index[0]
    const int*   dst = ei + N_EDGES;    // edge_index[1]
    const float* w1l = (const float*)d_in[2];
    const float* w1r = (const float*)d_in[3];
    const float* b1  = (const float*)d_in[4];
    const float* w2l = (const float*)d_in[5];
    const float* w2r = (const float*)d_in[6];
    const float* b2  = (const float*)d_in[7];
    const float* wc1 = (const float*)d_in[8];
    const float* bc1 = (const float*)d_in[9];
    const float* wc2 = (const float*)d_in[10];
    const float* bc2 = (const float*)d_in[11];
    float* out = (float*)d_out;

    // workspace layout (floats): cnt[N] | sum[64N] (reused both layers) | h1[64N] | h2[32N]
    float* w   = (float*)d_ws;
    float* cnt = w;
    float* sum = w + N_NODES;
    float* h1  = w + 65 * (size_t)N_NODES;
    float* h2  = w + 129 * (size_t)N_NODES;

    // zero cnt + sum in one shot (contiguous)
    hipMemsetAsync(cnt, 0, (size_t)65 * N_NODES * sizeof(float), stream);
    k_deg<<<(N_EDGES + 255) / 256, 256, 0, stream>>>(dst, cnt);
    k_scatter64<<<(N_EDGES * 16) / 256, 256, 0, stream>>>(src, dst, x, sum);
    k_layer1<<<N_NODES / 4, 256, 0, stream>>>(x, sum, cnt, w1l, w1r, b1, h1);

    hipMemsetAsync(sum, 0, (size_t)64 * N_NODES * sizeof(float), stream);
    k_scatter64<<<(N_EDGES * 16) / 256, 256, 0, stream>>>(src, dst, h1, sum);
    k_layer2<<<N_NODES / 8, 256, 0, stream>>>(h1, sum, cnt, w2l, w2r, b2, h2);

    k_classifier<<<(N_NODES + 255) / 256, 256, 0, stream>>>(h2, wc1, bc1, wc2, bc2, out);
}

// Round 2
// 340.421 us; speedup vs baseline: 4.5192x; 4.5192x over previous
//
#include <hip/hip_runtime.h>

#define N_NODES 50000
#define N_EDGES 800000
#define NB_SCAN 196   // ceil(50000/256)

// ---------------- histogram: deg[dst]++ ----------------
__global__ void k_hist(const int* __restrict__ dst, int* __restrict__ deg) {
    int e = blockIdx.x * blockDim.x + threadIdx.x;
    if (e < N_EDGES) atomicAdd(&deg[dst[e]], 1);
}

// ---------------- scan stage 1: per-256-block exclusive scan + block totals ----------------
__global__ void k_scan_block(const int* __restrict__ deg, int* __restrict__ off,
                             int* __restrict__ bsum) {
    __shared__ int tmp[256];
    int i = blockIdx.x * 256 + threadIdx.x;
    int v = (i < N_NODES) ? deg[i] : 0;
    tmp[threadIdx.x] = v;
    __syncthreads();
    int val = v;
    for (int d = 1; d < 256; d <<= 1) {
        int add = (threadIdx.x >= d) ? tmp[threadIdx.x - d] : 0;
        __syncthreads();
        val += add;
        tmp[threadIdx.x] = val;
        __syncthreads();
    }
    if (i < N_NODES) off[i] = val - v;               // exclusive within block
    if (threadIdx.x == 255) bsum[blockIdx.x] = val;  // block total
}

// ---------------- scan stage 2: exclusive scan of the 196 block totals ----------------
__global__ void k_scan_top(int* __restrict__ bsum) {
    __shared__ int tmp[256];
    int v = (threadIdx.x < NB_SCAN) ? bsum[threadIdx.x] : 0;
    tmp[threadIdx.x] = v;
    __syncthreads();
    int val = v;
    for (int d = 1; d < 256; d <<= 1) {
        int add = (threadIdx.x >= d) ? tmp[threadIdx.x - d] : 0;
        __syncthreads();
        val += add;
        tmp[threadIdx.x] = val;
        __syncthreads();
    }
    if (threadIdx.x < NB_SCAN) bsum[threadIdx.x] = val - v;  // exclusive
}

// ---------------- scan stage 3: add block offsets; init cursor ----------------
__global__ void k_scan_add(int* __restrict__ off, const int* __restrict__ bsum,
                           int* __restrict__ cursor) {
    int i = blockIdx.x * 256 + threadIdx.x;
    if (i < N_NODES) {
        int o = off[i] + bsum[blockIdx.x];
        off[i] = o;
        cursor[i] = o;
    }
}

// ---------------- bucket edges by dst: esrc[pos] = src ----------------
__global__ void k_bucket(const int* __restrict__ src, const int* __restrict__ dst,
                         int* __restrict__ cursor, int* __restrict__ esrc) {
    int e = blockIdx.x * blockDim.x + threadIdx.x;
    if (e < N_EDGES) {
        int p = atomicAdd(&cursor[dst[e]], 1);
        esrc[p] = src[e];
    }
}

// ---------------- gather-aggregate: mean[n] = avg over in-edges of feat[src] ----------------
// one wave per node (lane = channel), 4 nodes per 256-thread block; 4-way ILP.
__global__ void k_agg64(const int* __restrict__ off, const int* __restrict__ esrc,
                        const float* __restrict__ feat, float* __restrict__ mean) {
    int wv = threadIdx.x >> 6;
    int c  = threadIdx.x & 63;
    int node = blockIdx.x * 4 + wv;           // N % 4 == 0
    int s0 = off[node];
    int s1 = (node == N_NODES - 1) ? N_EDGES : off[node + 1];
    float a0 = 0.f, a1 = 0.f, a2 = 0.f, a3 = 0.f;
    int i = s0;
    for (; i + 3 < s1; i += 4) {
        int e0 = esrc[i], e1 = esrc[i + 1], e2 = esrc[i + 2], e3 = esrc[i + 3];
        a0 += feat[(size_t)e0 * 64 + c];
        a1 += feat[(size_t)e1 * 64 + c];
        a2 += feat[(size_t)e2 * 64 + c];
        a3 += feat[(size_t)e3 * 64 + c];
    }
    for (; i < s1; ++i) a0 += feat[(size_t)esrc[i] * 64 + c];
    float deg = (float)(s1 - s0);
    mean[(size_t)node * 64 + c] = (a0 + a1 + a2 + a3) / fmaxf(deg, 1.0f);
}

// ---------------- layer1: h1 = relu(mean @ wl + x @ wr + b), 64 -> 64 ----------------
__global__ void k_layer1(const float* __restrict__ x, const float* __restrict__ mean,
                         const float* __restrict__ wl, const float* __restrict__ wr,
                         const float* __restrict__ b, float* __restrict__ h1) {
    __shared__ float swl[64 * 64];
    __shared__ float swr[64 * 64];
    __shared__ float sx[4][64];
    __shared__ float sm[4][64];
    for (int i = threadIdx.x; i < 64 * 64; i += 256) { swl[i] = wl[i]; swr[i] = wr[i]; }
    int ln = threadIdx.x >> 6;
    int c  = threadIdx.x & 63;
    int node = blockIdx.x * 4 + ln;           // N % 4 == 0
    sx[ln][c] = x[(size_t)node * 64 + c];
    sm[ln][c] = mean[(size_t)node * 64 + c];
    __syncthreads();
    float acc = b[c];
#pragma unroll
    for (int k = 0; k < 64; ++k)
        acc = fmaf(sm[ln][k], swl[k * 64 + c], fmaf(sx[ln][k], swr[k * 64 + c], acc));
    h1[(size_t)node * 64 + c] = fmaxf(acc, 0.0f);
}

// ---------------- layer2: h2 = relu(mean @ wl + h1 @ wr + b), 64 -> 32 ----------------
__global__ void k_layer2(const float* __restrict__ h1, const float* __restrict__ mean,
                         const float* __restrict__ wl, const float* __restrict__ wr,
                         const float* __restrict__ b, float* __restrict__ h2) {
    __shared__ float swl[64 * 32];
    __shared__ float swr[64 * 32];
    __shared__ float sh[8][64];
    __shared__ float sm[8][64];
    for (int i = threadIdx.x; i < 64 * 32; i += 256) { swl[i] = wl[i]; swr[i] = wr[i]; }
    int ln = threadIdx.x >> 5;
    int c  = threadIdx.x & 31;
    int node = blockIdx.x * 8 + ln;           // N % 8 == 0
    sh[ln][c]      = h1[(size_t)node * 64 + c];
    sh[ln][c + 32] = h1[(size_t)node * 64 + c + 32];
    sm[ln][c]      = mean[(size_t)node * 64 + c];
    sm[ln][c + 32] = mean[(size_t)node * 64 + c + 32];
    __syncthreads();
    float acc = b[c];
#pragma unroll
    for (int k = 0; k < 64; ++k)
        acc = fmaf(sm[ln][k], swl[k * 32 + c], fmaf(sh[ln][k], swr[k * 32 + c], acc));
    h2[(size_t)node * 32 + c] = fmaxf(acc, 0.0f);
}

// ---------------- classifier: out = relu(h2 @ wc1 + bc1) @ wc2 + bc2 ----------------
__global__ void k_classifier(const float* __restrict__ h2,
                             const float* __restrict__ wc1, const float* __restrict__ bc1,
                             const float* __restrict__ wc2, const float* __restrict__ bc2,
                             float* __restrict__ out) {
    __shared__ float s1[32 * 16];
    __shared__ float sb1[16];
    __shared__ float s2[16 * 2];
    __shared__ float sb2[2];
    int t = threadIdx.x;
    for (int i = t; i < 32 * 16; i += 256) s1[i] = wc1[i];
    if (t < 16) sb1[t] = bc1[t];
    if (t < 32) s2[t] = wc2[t];
    if (t < 2)  sb2[t] = bc2[t];
    __syncthreads();
    int node = blockIdx.x * 256 + t;
    if (node >= N_NODES) return;
    float h[32];
    const float4* hp = (const float4*)(h2 + (size_t)node * 32);
#pragma unroll
    for (int i = 0; i < 8; ++i) {
        float4 v = hp[i];
        h[i * 4 + 0] = v.x; h[i * 4 + 1] = v.y; h[i * 4 + 2] = v.z; h[i * 4 + 3] = v.w;
    }
    float o0 = sb2[0], o1 = sb2[1];
#pragma unroll
    for (int j = 0; j < 16; ++j) {
        float a = sb1[j];
#pragma unroll
        for (int k = 0; k < 32; ++k) a = fmaf(h[k], s1[k * 16 + j], a);
        a = fmaxf(a, 0.0f);
        o0 = fmaf(a, s2[j * 2 + 0], o0);
        o1 = fmaf(a, s2[j * 2 + 1], o1);
    }
    *(float2*)(out + (size_t)node * 2) = make_float2(o0, o1);
}

extern "C" void kernel_launch(void* const* d_in, const int* in_sizes, int n_in,
                              void* d_out, int out_size, void* d_ws, size_t ws_size,
                              hipStream_t stream) {
    const float* x   = (const float*)d_in[0];
    const int*   ei  = (const int*)d_in[1];
    const int*   src = ei;              // edge_index[0]
    const int*   dst = ei + N_EDGES;    // edge_index[1]
    const float* w1l = (const float*)d_in[2];
    const float* w1r = (const float*)d_in[3];
    const float* b1  = (const float*)d_in[4];
    const float* w2l = (const float*)d_in[5];
    const float* w2r = (const float*)d_in[6];
    const float* b2  = (const float*)d_in[7];
    const float* wc1 = (const float*)d_in[8];
    const float* bc1 = (const float*)d_in[9];
    const float* wc2 = (const float*)d_in[10];
    const float* bc2 = (const float*)d_in[11];
    float* out = (float*)d_out;

    // workspace layout (4B units):
    //   ints:   deg[N] | off[N] | cursor[N] | bsum[256] | esrc[E]
    //   floats: mean[64N] | h1[64N] | h2[32N]
    int*   wi     = (int*)d_ws;
    int*   deg    = wi;
    int*   off    = wi + N_NODES;
    int*   cursor = wi + 2 * N_NODES;
    int*   bsum   = wi + 3 * N_NODES;
    int*   esrc   = wi + 3 * N_NODES + 256;
    float* mean   = (float*)(esrc + N_EDGES);
    float* h1     = mean + (size_t)64 * N_NODES;
    float* h2     = h1 + (size_t)64 * N_NODES;

    const int EB = (N_EDGES + 255) / 256;

    // ---- build CSR (dst-bucketed src list) ----
    hipMemsetAsync(deg, 0, N_NODES * sizeof(int), stream);
    k_hist<<<EB, 256, 0, stream>>>(dst, deg);
    k_scan_block<<<NB_SCAN, 256, 0, stream>>>(deg, off, bsum);
    k_scan_top<<<1, 256, 0, stream>>>(bsum);
    k_scan_add<<<NB_SCAN, 256, 0, stream>>>(off, bsum, cursor);
    k_bucket<<<EB, 256, 0, stream>>>(src, dst, cursor, esrc);

    // ---- layer 1 ----
    k_agg64<<<N_NODES / 4, 256, 0, stream>>>(off, esrc, x, mean);
    k_layer1<<<N_NODES / 4, 256, 0, stream>>>(x, mean, w1l, w1r, b1, h1);

    // ---- layer 2 ----
    k_agg64<<<N_NODES / 4, 256, 0, stream>>>(off, esrc, h1, mean);
    k_layer2<<<N_NODES / 8, 256, 0, stream>>>(h1, mean, w2l, w2r, b2, h2);

    // ---- classifier ----
    k_classifier<<<(N_NODES + 255) / 256, 256, 0, stream>>>(h2, wc1, bc1, wc2, bc2, out);
}

// Round 3
// 293.482 us; speedup vs baseline: 5.2420x; 1.1599x over previous
//
#include <hip/hip_runtime.h>

#define N_NODES 50000
#define N_EDGES 800000
#define NB_SCAN 196          // ceil(50000/256)
#define NBINS   391          // ceil(50000/128), 128 dst nodes per bin
#define EPB     4096         // edges per block in pass A
#define NBLK_A  ((N_EDGES + EPB - 1) / EPB)
#define MAXSEG  4096         // pass-B LDS segment capacity (avg 2046, Poisson)

// ---------------- degree histogram: deg[dst]++ ----------------
__global__ void k_hist(const int* __restrict__ dst, int* __restrict__ deg) {
    int e = blockIdx.x * blockDim.x + threadIdx.x;
    if (e < N_EDGES) atomicAdd(&deg[dst[e]], 1);
}

// ---------------- scan stage 1 ----------------
__global__ void k_scan_block(const int* __restrict__ deg, int* __restrict__ off,
                             int* __restrict__ bsum) {
    __shared__ int tmp[256];
    int i = blockIdx.x * 256 + threadIdx.x;
    int v = (i < N_NODES) ? deg[i] : 0;
    tmp[threadIdx.x] = v;
    __syncthreads();
    int val = v;
    for (int d = 1; d < 256; d <<= 1) {
        int add = (threadIdx.x >= d) ? tmp[threadIdx.x - d] : 0;
        __syncthreads();
        val += add;
        tmp[threadIdx.x] = val;
        __syncthreads();
    }
    if (i < N_NODES) off[i] = val - v;
    if (threadIdx.x == 255) bsum[blockIdx.x] = val;
}

// ---------------- scan stage 2 ----------------
__global__ void k_scan_top(int* __restrict__ bsum) {
    __shared__ int tmp[256];
    int v = (threadIdx.x < NB_SCAN) ? bsum[threadIdx.x] : 0;
    tmp[threadIdx.x] = v;
    __syncthreads();
    int val = v;
    for (int d = 1; d < 256; d <<= 1) {
        int add = (threadIdx.x >= d) ? tmp[threadIdx.x - d] : 0;
        __syncthreads();
        val += add;
        tmp[threadIdx.x] = val;
        __syncthreads();
    }
    if (threadIdx.x < NB_SCAN) bsum[threadIdx.x] = val - v;
}

// ---------------- scan stage 3: finalize off; init fallback cursors + bin bases ----------------
__global__ void k_scan_add(int* __restrict__ off, const int* __restrict__ bsum,
                           int* __restrict__ gcur, int* __restrict__ bincur) {
    int i = blockIdx.x * 256 + threadIdx.x;
    if (i < N_NODES) {
        int o = off[i] + bsum[blockIdx.x];
        off[i] = o;
        gcur[i] = o;
        if ((i & 127) == 0) bincur[i >> 7] = o;   // bin base = off at node 128*b
    }
}

// ---------------- pass A: LDS-staged bin scatter (bin = dst>>7) ----------------
// Writes bin-grouped runs -> mostly full-line global writes (kills the 16x
// write amplification of 4B random scatter across XCD L2s).
__global__ void k_binA(const int* __restrict__ src, const int* __restrict__ dst,
                       int* __restrict__ bincur, int* __restrict__ binned) {
    __shared__ int cnt[NBINS];
    __shared__ int sscan[NBINS];
    __shared__ int lpos[NBINS];
    __shared__ int base[NBINS];
    __shared__ int stage[EPB];
    __shared__ unsigned short sbin[EPB];
    int t = threadIdx.x;
    int blkbase = blockIdx.x * EPB;
    int nE = min(EPB, N_EDGES - blkbase);
    for (int i = t; i < NBINS; i += 256) cnt[i] = 0;
    __syncthreads();
    int sv[16], dv[16];
#pragma unroll
    for (int k = 0; k < 16; ++k) {
        int e = blkbase + t + k * 256;
        if (e < N_EDGES) {
            sv[k] = src[e];
            dv[k] = dst[e];
            atomicAdd(&cnt[dv[k] >> 7], 1);
        } else dv[k] = -1;
    }
    __syncthreads();
    if (t == 0) {                    // serial exclusive scan of 391 bins (~1us, parallel across blocks)
        int run = 0;
        for (int b = 0; b < NBINS; ++b) { sscan[b] = run; run += cnt[b]; }
    }
    __syncthreads();
    for (int b = t; b < NBINS; b += 256) {
        lpos[b] = sscan[b];
        if (cnt[b] > 0) base[b] = atomicAdd(&bincur[b], cnt[b]);
    }
    __syncthreads();
#pragma unroll
    for (int k = 0; k < 16; ++k) {
        if (dv[k] >= 0) {
            int b = dv[k] >> 7;
            int p = atomicAdd(&lpos[b], 1);
            stage[p] = (sv[k] & 0xFFFF) | ((dv[k] & 127) << 16);  // src<2^16, dstLocal<128
            sbin[p] = (unsigned short)b;
        }
    }
    __syncthreads();
    for (int i = t; i < nE; i += 256) {
        int b = sbin[i];
        binned[base[b] + (i - sscan[b])] = stage[i];
    }
}

// ---------------- pass B: per-bin counting sort (single-owner segment) ----------------
__global__ void k_binB(const int* __restrict__ off, const int* __restrict__ binned,
                       int* __restrict__ gcur, int* __restrict__ esrc) {
    __shared__ int cur[128];
    __shared__ int buf[MAXSEG];
    int b = blockIdx.x, t = threadIdx.x;
    int n0 = b << 7;
    int seg0 = off[n0];
    int nend = n0 + 128;
    int seg1 = (nend >= N_NODES) ? N_EDGES : off[nend];
    int n = seg1 - seg0;
    if (t < 128) {
        int node = n0 + t;
        cur[t] = ((node < N_NODES) ? off[node] : N_EDGES) - seg0;
    }
    __syncthreads();
    if (n <= MAXSEG) {
        for (int i = t; i < n; i += 256) {
            int v = binned[seg0 + i];
            int p = atomicAdd(&cur[v >> 16], 1);   // LDS atomic
            buf[p] = v & 0xFFFF;
        }
        __syncthreads();
        for (int i = t; i < n; i += 256) esrc[seg0 + i] = buf[i];  // coalesced
    } else {  // statistically unreachable overflow fallback
        for (int i = t; i < n; i += 256) {
            int v = binned[seg0 + i];
            int node = n0 + (v >> 16);
            int p = atomicAdd(&gcur[node], 1);
            esrc[p] = v & 0xFFFF;
        }
    }
}

// ---------------- fused agg(x) + layer1: h1 = relu(mean @ wl + x @ wr + b) ----------------
// 4 waves/block, one node per wave, lane = channel.
__global__ void k_agg_layer1(const int* __restrict__ off, const int* __restrict__ esrc,
                             const float* __restrict__ x,
                             const float* __restrict__ wl, const float* __restrict__ wr,
                             const float* __restrict__ b, float* __restrict__ h1) {
    __shared__ float swl[4096], swr[4096];
    __shared__ float sm[4][64], sx[4][64];
    int t = threadIdx.x;
    for (int i = t; i < 4096; i += 256) { swl[i] = wl[i]; swr[i] = wr[i]; }
    int wv = t >> 6, c = t & 63;
    int node = blockIdx.x * 4 + wv;          // N % 4 == 0
    int s0 = off[node];
    int s1 = (node == N_NODES - 1) ? N_EDGES : off[node + 1];
    float a0 = 0.f, a1 = 0.f, a2 = 0.f, a3 = 0.f;
    int i = s0;
    for (; i + 3 < s1; i += 4) {
        int e0 = esrc[i], e1 = esrc[i + 1], e2 = esrc[i + 2], e3 = esrc[i + 3];
        a0 += x[(size_t)e0 * 64 + c];
        a1 += x[(size_t)e1 * 64 + c];
        a2 += x[(size_t)e2 * 64 + c];
        a3 += x[(size_t)e3 * 64 + c];
    }
    for (; i < s1; ++i) a0 += x[(size_t)esrc[i] * 64 + c];
    float deg = (float)(s1 - s0);
    sm[wv][c] = (a0 + a1 + a2 + a3) / fmaxf(deg, 1.0f);
    sx[wv][c] = x[(size_t)node * 64 + c];
    __syncthreads();
    float acc = b[c];
#pragma unroll
    for (int k = 0; k < 64; ++k)
        acc = fmaf(sm[wv][k], swl[k * 64 + c], fmaf(sx[wv][k], swr[k * 64 + c], acc));
    h1[(size_t)node * 64 + c] = fmaxf(acc, 0.0f);
}

// ---------------- z = h1 @ w2_l  (linearity: mean(h1)@W == mean(h1@W); 32ch agg) ----------------
__global__ void k_ztrans(const float* __restrict__ h1, const float* __restrict__ w2l,
                         float* __restrict__ z) {
    __shared__ float sw[64 * 32];
    __shared__ float sh[8][64];
    int t = threadIdx.x;
    for (int i = t; i < 2048; i += 256) sw[i] = w2l[i];
    int ln = t >> 5, c = t & 31;
    int node = blockIdx.x * 8 + ln;          // N % 8 == 0
    sh[ln][c]      = h1[(size_t)node * 64 + c];
    sh[ln][c + 32] = h1[(size_t)node * 64 + c + 32];
    __syncthreads();
    float acc = 0.f;
#pragma unroll
    for (int k = 0; k < 64; ++k) acc = fmaf(sh[ln][k], sw[k * 32 + c], acc);
    z[(size_t)node * 32 + c] = acc;
}

// ---------------- fused agg(z) + layer2 + classifier ----------------
// 8 nodes/block; half-wave (32 lanes) per node, lane = channel.
__global__ void k_agg_layer2_cls(const int* __restrict__ off, const int* __restrict__ esrc,
                                 const float* __restrict__ z, const float* __restrict__ h1,
                                 const float* __restrict__ w2r, const float* __restrict__ b2,
                                 const float* __restrict__ wc1, const float* __restrict__ bc1,
                                 const float* __restrict__ wc2, const float* __restrict__ bc2,
                                 float* __restrict__ out) {
    __shared__ float swr[64 * 32];
    __shared__ float sc1[32 * 16];
    __shared__ float sm[8][32], sh[8][64], sh2[8][32], sh3[8][16];
    int t = threadIdx.x;
    for (int i = t; i < 2048; i += 256) swr[i] = w2r[i];
    for (int i = t; i < 512; i += 256) sc1[i] = wc1[i];
    int ln = t >> 5, c = t & 31;
    int node = blockIdx.x * 8 + ln;          // N % 8 == 0
    int s0 = off[node];
    int s1 = (node == N_NODES - 1) ? N_EDGES : off[node + 1];
    float a0 = 0.f, a1 = 0.f, a2 = 0.f, a3 = 0.f;
    int i = s0;
    for (; i + 3 < s1; i += 4) {
        int e0 = esrc[i], e1 = esrc[i + 1], e2 = esrc[i + 2], e3 = esrc[i + 3];
        a0 += z[(size_t)e0 * 32 + c];
        a1 += z[(size_t)e1 * 32 + c];
        a2 += z[(size_t)e2 * 32 + c];
        a3 += z[(size_t)e3 * 32 + c];
    }
    for (; i < s1; ++i) a0 += z[(size_t)esrc[i] * 32 + c];
    float deg = (float)(s1 - s0);
    sm[ln][c] = (a0 + a1 + a2 + a3) / fmaxf(deg, 1.0f);
    sh[ln][c]      = h1[(size_t)node * 64 + c];
    sh[ln][c + 32] = h1[(size_t)node * 64 + c + 32];
    __syncthreads();
    float acc = sm[ln][c] + b2[c];
#pragma unroll
    for (int k = 0; k < 64; ++k) acc = fmaf(sh[ln][k], swr[k * 32 + c], acc);
    sh2[ln][c] = fmaxf(acc, 0.0f);
    __syncthreads();
    if (c < 16) {
        float a = bc1[c];
#pragma unroll
        for (int k = 0; k < 32; ++k) a = fmaf(sh2[ln][k], sc1[k * 16 + c], a);
        sh3[ln][c] = fmaxf(a, 0.0f);
    }
    __syncthreads();
    if (c < 2) {
        float o = bc2[c];
#pragma unroll
        for (int k = 0; k < 16; ++k) o = fmaf(sh3[ln][k], wc2[k * 2 + c], o);
        out[(size_t)node * 2 + c] = o;
    }
}

extern "C" void kernel_launch(void* const* d_in, const int* in_sizes, int n_in,
                              void* d_out, int out_size, void* d_ws, size_t ws_size,
                              hipStream_t stream) {
    const float* x   = (const float*)d_in[0];
    const int*   ei  = (const int*)d_in[1];
    const int*   src = ei;
    const int*   dst = ei + N_EDGES;
    const float* w1l = (const float*)d_in[2];
    const float* w1r = (const float*)d_in[3];
    const float* b1  = (const float*)d_in[4];
    const float* w2l = (const float*)d_in[5];
    const float* w2r = (const float*)d_in[6];
    const float* b2  = (const float*)d_in[7];
    const float* wc1 = (const float*)d_in[8];
    const float* bc1 = (const float*)d_in[9];
    const float* wc2 = (const float*)d_in[10];
    const float* bc2 = (const float*)d_in[11];
    float* out = (float*)d_out;

    // ws layout (4B units):
    //   deg[N] | off[N] | gcur[N] | bsum[256] | bincur[512] | binned[E] | esrc[E] | h1[64N] | z[32N]
    int*   wi     = (int*)d_ws;
    int*   deg    = wi;
    int*   off    = wi + N_NODES;
    int*   gcur   = wi + 2 * N_NODES;
    int*   bsum   = wi + 3 * N_NODES;
    int*   bincur = wi + 3 * N_NODES + 256;
    int*   binned = wi + 3 * N_NODES + 768;
    int*   esrc   = binned + N_EDGES;
    float* h1     = (float*)(esrc + N_EDGES);
    float* z      = h1 + (size_t)64 * N_NODES;

    const int EB = (N_EDGES + 255) / 256;

    // ---- CSR build ----
    hipMemsetAsync(deg, 0, N_NODES * sizeof(int), stream);
    k_hist<<<EB, 256, 0, stream>>>(dst, deg);
    k_scan_block<<<NB_SCAN, 256, 0, stream>>>(deg, off, bsum);
    k_scan_top<<<1, 256, 0, stream>>>(bsum);
    k_scan_add<<<NB_SCAN, 256, 0, stream>>>(off, bsum, gcur, bincur);
    k_binA<<<NBLK_A, 256, 0, stream>>>(src, dst, bincur, binned);
    k_binB<<<NBINS, 256, 0, stream>>>(off, binned, gcur, esrc);

    // ---- layer 1 (fused agg + dual GEMM) ----
    k_agg_layer1<<<N_NODES / 4, 256, 0, stream>>>(off, esrc, x, w1l, w1r, b1, h1);

    // ---- layer 2 (pre-transform, fused agg + GEMM + classifier) ----
    k_ztrans<<<N_NODES / 8, 256, 0, stream>>>(h1, w2l, z);
    k_agg_layer2_cls<<<N_NODES / 8, 256, 0, stream>>>(off, esrc, z, h1, w2r, b2,
                                                      wc1, bc1, wc2, bc2, out);
}

// Round 4
// 251.920 us; speedup vs baseline: 6.1068x; 1.1650x over previous
//
#include <hip/hip_runtime.h>

#define N_NODES 50000
#define N_EDGES 800000
#define NBINS   391          // ceil(50000/128), 128 dst nodes per bin
#define EPB     4096         // edges per block (bhist / binA)
#define NBLK_E  ((N_EDGES + EPB - 1) / EPB)
#define MAXSEG  4096         // pass-B LDS segment capacity (mean 2046, ~45 sigma margin)

// ---------------- bin-level histogram: bincnt[dst>>7]++ (LDS-staged) ----------------
__global__ void k_bhist(const int* __restrict__ dst, int* __restrict__ bincnt) {
    __shared__ int cnt[NBINS];
    int t = threadIdx.x;
    for (int i = t; i < NBINS; i += 256) cnt[i] = 0;
    __syncthreads();
    int base = blockIdx.x * EPB;
    int nE = min(EPB, N_EDGES - base);
    for (int i = t; i < nE; i += 256) atomicAdd(&cnt[dst[base + i] >> 7], 1);
    __syncthreads();
    for (int i = t; i < NBINS; i += 256) if (cnt[i]) atomicAdd(&bincnt[i], cnt[i]);
}

// ---------------- exclusive scan of 391 bin counts; init binoff + bincur ----------------
__global__ void k_bscan(const int* __restrict__ bincnt, int* __restrict__ binoff,
                        int* __restrict__ bincur) {
    __shared__ int tmp[512];
    int t = threadIdx.x;
    int v = (t < NBINS) ? bincnt[t] : 0;
    tmp[t] = v;
    __syncthreads();
    int val = v;
    for (int d = 1; d < 512; d <<= 1) {
        int add = (t >= d) ? tmp[t - d] : 0;
        __syncthreads();
        val += add;
        tmp[t] = val;
        __syncthreads();
    }
    if (t < NBINS) { binoff[t] = val - v; bincur[t] = val - v; }
    if (t == NBINS - 1) binoff[NBINS] = val;   // == N_EDGES
}

// ---------------- pass A: LDS-staged bin scatter (bin = dst>>7) ----------------
__global__ void k_binA(const int* __restrict__ src, const int* __restrict__ dst,
                       int* __restrict__ bincur, int* __restrict__ binned) {
    __shared__ int cnt[NBINS];
    __shared__ int sscan[NBINS];
    __shared__ int lpos[NBINS];
    __shared__ int base[NBINS];
    __shared__ int stage[EPB];
    __shared__ unsigned short sbin[EPB];
    int t = threadIdx.x;
    int blkbase = blockIdx.x * EPB;
    int nE = min(EPB, N_EDGES - blkbase);
    for (int i = t; i < NBINS; i += 256) cnt[i] = 0;
    __syncthreads();
    int sv[16], dv[16];
#pragma unroll
    for (int k = 0; k < 16; ++k) {
        int e = blkbase + t + k * 256;
        if (e < N_EDGES) {
            sv[k] = src[e];
            dv[k] = dst[e];
            atomicAdd(&cnt[dv[k] >> 7], 1);
        } else dv[k] = -1;
    }
    __syncthreads();
    if (t == 0) {
        int run = 0;
        for (int b = 0; b < NBINS; ++b) { sscan[b] = run; run += cnt[b]; }
    }
    __syncthreads();
    for (int b = t; b < NBINS; b += 256) {
        lpos[b] = sscan[b];
        if (cnt[b] > 0) base[b] = atomicAdd(&bincur[b], cnt[b]);
    }
    __syncthreads();
#pragma unroll
    for (int k = 0; k < 16; ++k) {
        if (dv[k] >= 0) {
            int b = dv[k] >> 7;
            int p = atomicAdd(&lpos[b], 1);
            stage[p] = (sv[k] & 0xFFFF) | ((dv[k] & 127) << 16);  // src < 2^16
            sbin[p] = (unsigned short)b;
        }
    }
    __syncthreads();
    for (int i = t; i < nE; i += 256) {
        int b = sbin[i];
        binned[base[b] + (i - sscan[b])] = stage[i];
    }
}

// ---------------- pass B: per-bin counting sort; also derives off[] ----------------
__global__ void k_binB(const int* __restrict__ binoff, const int* __restrict__ binned,
                       int* __restrict__ off, int* __restrict__ esrc) {
    __shared__ int cnt[128];
    __shared__ int tmp[128];
    __shared__ int cur[128];
    __shared__ int buf[MAXSEG];
    int b = blockIdx.x, t = threadIdx.x;
    int n0 = b << 7;
    int seg0 = binoff[b], seg1 = binoff[b + 1];
    int n = seg1 - seg0;
    if (t < 128) cnt[t] = 0;
    __syncthreads();
    for (int i = t; i < n; i += 256) atomicAdd(&cnt[binned[seg0 + i] >> 16], 1);
    __syncthreads();
    // exclusive scan of 128 node-degrees
    int v = (t < 128) ? cnt[t] : 0;
    if (t < 128) tmp[t] = v;
    __syncthreads();
    int val = v;
    for (int d = 1; d < 128; d <<= 1) {
        int add = (t >= d && t < 128) ? tmp[t - d] : 0;
        __syncthreads();
        if (t < 128) { val += add; tmp[t] = val; }
        __syncthreads();
    }
    if (t < 128) {
        int excl = val - v;
        cur[t] = excl;
        int node = n0 + t;
        if (node < N_NODES) off[node] = seg0 + excl;
    }
    __syncthreads();
    if (n <= MAXSEG) {
        for (int i = t; i < n; i += 256) {
            int w = binned[seg0 + i];
            int p = atomicAdd(&cur[w >> 16], 1);    // LDS atomic
            buf[p] = w & 0xFFFF;
        }
        __syncthreads();
        for (int i = t; i < n; i += 256) esrc[seg0 + i] = buf[i];  // coalesced
    } else {  // statistically unreachable
        for (int i = t; i < n; i += 256) {
            int w = binned[seg0 + i];
            int p = atomicAdd(&cur[w >> 16], 1);
            esrc[seg0 + p] = w & 0xFFFF;
        }
    }
}

// ---------------- fused agg(x) + layer1: h1 = relu(mean @ wl + x @ wr + b) ----------------
// 512 threads = 8 waves, one node per wave. Gather: lane = (edge-in-quad, ch-group),
// each wave-load covers 4 edges x 64B (float4/lane) -> 4x fewer loads, 1KB/inst.
__global__ __launch_bounds__(512) void k_agg_layer1(
        const int* __restrict__ off, const int* __restrict__ esrc,
        const float* __restrict__ x,
        const float* __restrict__ wl, const float* __restrict__ wr,
        const float* __restrict__ b, float* __restrict__ h1) {
    __shared__ float swl[4096], swr[4096];
    __shared__ float sm[8][64], sx[8][64];
    int t = threadIdx.x;
    for (int i = t; i < 1024; i += 512) {
        ((float4*)swl)[i] = ((const float4*)wl)[i];
        ((float4*)swr)[i] = ((const float4*)wr)[i];
    }
    int wv = t >> 6, lane = t & 63;
    int node = blockIdx.x * 8 + wv;          // N % 8 == 0
    int s0 = off[node];
    int s1 = (node == N_NODES - 1) ? N_EDGES : off[node + 1];
    int eg = lane >> 4;                       // 0..3: which edge of the quad
    int cg = (lane & 15) << 2;                // channel group *4
    float ax0 = 0.f, ay0 = 0.f, az0 = 0.f, aw0 = 0.f;
    float ax1 = 0.f, ay1 = 0.f, az1 = 0.f, aw1 = 0.f;
    float ax2 = 0.f, ay2 = 0.f, az2 = 0.f, aw2 = 0.f;
    float ax3 = 0.f, ay3 = 0.f, az3 = 0.f, aw3 = 0.f;
    for (int i = s0; i < s1; i += 16) {
        int i0 = i + eg, i1 = i + 4 + eg, i2 = i + 8 + eg, i3 = i + 12 + eg;
        if (i0 < s1) {
            const float4 v = *(const float4*)(x + (size_t)esrc[i0] * 64 + cg);
            ax0 += v.x; ay0 += v.y; az0 += v.z; aw0 += v.w;
        }
        if (i1 < s1) {
            const float4 v = *(const float4*)(x + (size_t)esrc[i1] * 64 + cg);
            ax1 += v.x; ay1 += v.y; az1 += v.z; aw1 += v.w;
        }
        if (i2 < s1) {
            const float4 v = *(const float4*)(x + (size_t)esrc[i2] * 64 + cg);
            ax2 += v.x; ay2 += v.y; az2 += v.z; aw2 += v.w;
        }
        if (i3 < s1) {
            const float4 v = *(const float4*)(x + (size_t)esrc[i3] * 64 + cg);
            ax3 += v.x; ay3 += v.y; az3 += v.z; aw3 += v.w;
        }
    }
    float sxv = ax0 + ax1 + ax2 + ax3;
    float syv = ay0 + ay1 + ay2 + ay3;
    float szv = az0 + az1 + az2 + az3;
    float swv = aw0 + aw1 + aw2 + aw3;
    // reduce across the 4 edge-slots (lane bits 4,5)
    sxv += __shfl_xor(sxv, 16); syv += __shfl_xor(syv, 16);
    szv += __shfl_xor(szv, 16); swv += __shfl_xor(swv, 16);
    sxv += __shfl_xor(sxv, 32); syv += __shfl_xor(syv, 32);
    szv += __shfl_xor(szv, 32); swv += __shfl_xor(swv, 32);
    float inv = 1.0f / fmaxf((float)(s1 - s0), 1.0f);
    if (eg == 0) {
        sm[wv][cg + 0] = sxv * inv; sm[wv][cg + 1] = syv * inv;
        sm[wv][cg + 2] = szv * inv; sm[wv][cg + 3] = swv * inv;
    }
    sx[wv][lane] = x[(size_t)node * 64 + lane];
    __syncthreads();
    float acc = b[lane];
#pragma unroll
    for (int k = 0; k < 64; ++k)
        acc = fmaf(sm[wv][k], swl[k * 64 + lane], fmaf(sx[wv][k], swr[k * 64 + lane], acc));
    h1[(size_t)node * 64 + lane] = fmaxf(acc, 0.0f);
}

// ---------------- z = h1 @ w2_l  (linearity: mean(h1)@W == mean(h1@W)) ----------------
__global__ void k_ztrans(const float* __restrict__ h1, const float* __restrict__ w2l,
                         float* __restrict__ z) {
    __shared__ float sw[64 * 32];
    __shared__ float sh[8][64];
    int t = threadIdx.x;
    for (int i = t; i < 2048; i += 256) sw[i] = w2l[i];
    int ln = t >> 5, c = t & 31;
    int node = blockIdx.x * 8 + ln;          // N % 8 == 0
    sh[ln][c]      = h1[(size_t)node * 64 + c];
    sh[ln][c + 32] = h1[(size_t)node * 64 + c + 32];
    __syncthreads();
    float acc = 0.f;
#pragma unroll
    for (int k = 0; k < 64; ++k) acc = fmaf(sh[ln][k], sw[k * 32 + c], acc);
    z[(size_t)node * 32 + c] = acc;
}

// ---------------- fused agg(z) + layer2 + classifier ----------------
// 512 threads = 8 waves, one node per wave. Gather: 8 edges x 32B per wave-load.
__global__ __launch_bounds__(512) void k_agg_layer2_cls(
        const int* __restrict__ off, const int* __restrict__ esrc,
        const float* __restrict__ z, const float* __restrict__ h1,
        const float* __restrict__ w2r, const float* __restrict__ b2,
        const float* __restrict__ wc1, const float* __restrict__ bc1,
        const float* __restrict__ wc2, const float* __restrict__ bc2,
        float* __restrict__ out) {
    __shared__ float swr[64 * 32];
    __shared__ float sc1[32 * 16];
    __shared__ float sm[8][32], sh[8][64], sh2[8][32], sh3[8][16];
    int t = threadIdx.x;
    for (int i = t; i < 2048; i += 512) swr[i] = w2r[i];
    if (t < 512) sc1[t] = wc1[t];
    int wv = t >> 6, lane = t & 63;
    int node = blockIdx.x * 8 + wv;          // N % 8 == 0
    int s0 = off[node];
    int s1 = (node == N_NODES - 1) ? N_EDGES : off[node + 1];
    int eg = lane >> 3;                       // 0..7: which edge of the octet
    int cg = (lane & 7) << 2;                 // channel group *4 (32ch rows)
    float ax0 = 0.f, ay0 = 0.f, az0 = 0.f, aw0 = 0.f;
    float ax1 = 0.f, ay1 = 0.f, az1 = 0.f, aw1 = 0.f;
    for (int i = s0; i < s1; i += 16) {
        int i0 = i + eg, i1 = i + 8 + eg;
        if (i0 < s1) {
            const float4 v = *(const float4*)(z + (size_t)esrc[i0] * 32 + cg);
            ax0 += v.x; ay0 += v.y; az0 += v.z; aw0 += v.w;
        }
        if (i1 < s1) {
            const float4 v = *(const float4*)(z + (size_t)esrc[i1] * 32 + cg);
            ax1 += v.x; ay1 += v.y; az1 += v.z; aw1 += v.w;
        }
    }
    float sxv = ax0 + ax1, syv = ay0 + ay1, szv = az0 + az1, swv = aw0 + aw1;
    // reduce across the 8 edge-slots (lane bits 3,4,5)
    sxv += __shfl_xor(sxv, 8);  syv += __shfl_xor(syv, 8);
    szv += __shfl_xor(szv, 8);  swv += __shfl_xor(swv, 8);
    sxv += __shfl_xor(sxv, 16); syv += __shfl_xor(syv, 16);
    szv += __shfl_xor(szv, 16); swv += __shfl_xor(swv, 16);
    sxv += __shfl_xor(sxv, 32); syv += __shfl_xor(syv, 32);
    szv += __shfl_xor(szv, 32); swv += __shfl_xor(swv, 32);
    float inv = 1.0f / fmaxf((float)(s1 - s0), 1.0f);
    if (eg == 0) {
        sm[wv][cg + 0] = sxv * inv; sm[wv][cg + 1] = syv * inv;
        sm[wv][cg + 2] = szv * inv; sm[wv][cg + 3] = swv * inv;
    }
    sh[wv][lane] = h1[(size_t)node * 64 + lane];
    __syncthreads();
    // split-k GEMM: c = lane&31, half = lane>>5 covers k in [32*half, 32*half+32)
    int c = lane & 31, half = lane >> 5;
    float p = 0.f;
#pragma unroll
    for (int k = 0; k < 32; ++k) {
        int kk = half * 32 + k;
        p = fmaf(sh[wv][kk], swr[kk * 32 + c], p);
    }
    p += __shfl_xor(p, 32);
    if (half == 0) sh2[wv][c] = fmaxf(p + sm[wv][c] + b2[c], 0.0f);
    __syncthreads();
    if (lane < 16) {
        float a = bc1[lane];
#pragma unroll
        for (int k = 0; k < 32; ++k) a = fmaf(sh2[wv][k], sc1[k * 16 + lane], a);
        sh3[wv][lane] = fmaxf(a, 0.0f);
    }
    __syncthreads();
    if (lane < 2) {
        float o = bc2[lane];
#pragma unroll
        for (int k = 0; k < 16; ++k) o = fmaf(sh3[wv][k], wc2[k * 2 + lane], o);
        out[(size_t)node * 2 + lane] = o;
    }
}

extern "C" void kernel_launch(void* const* d_in, const int* in_sizes, int n_in,
                              void* d_out, int out_size, void* d_ws, size_t ws_size,
                              hipStream_t stream) {
    const float* x   = (const float*)d_in[0];
    const int*   ei  = (const int*)d_in[1];
    const int*   src = ei;
    const int*   dst = ei + N_EDGES;
    const float* w1l = (const float*)d_in[2];
    const float* w1r = (const float*)d_in[3];
    const float* b1  = (const float*)d_in[4];
    const float* w2l = (const float*)d_in[5];
    const float* w2r = (const float*)d_in[6];
    const float* b2  = (const float*)d_in[7];
    const float* wc1 = (const float*)d_in[8];
    const float* bc1 = (const float*)d_in[9];
    const float* wc2 = (const float*)d_in[10];
    const float* bc2 = (const float*)d_in[11];
    float* out = (float*)d_out;

    // ws layout (4B units):
    //   bincnt[392] | binoff[392] | bincur[392] | off[N] | binned[E] | esrc[E] | h1[64N] | z[32N]
    int*   wi     = (int*)d_ws;
    int*   bincnt = wi;
    int*   binoff = wi + 392;
    int*   bincur = wi + 784;
    int*   off    = wi + 1176;
    int*   binned = off + N_NODES;
    int*   esrc   = binned + N_EDGES;
    float* h1     = (float*)(esrc + N_EDGES);
    float* z      = h1 + (size_t)64 * N_NODES;

    // ---- CSR build (bin-granular hist/scan; binB derives per-node off) ----
    hipMemsetAsync(bincnt, 0, 392 * sizeof(int), stream);
    k_bhist<<<NBLK_E, 256, 0, stream>>>(dst, bincnt);
    k_bscan<<<1, 512, 0, stream>>>(bincnt, binoff, bincur);
    k_binA<<<NBLK_E, 256, 0, stream>>>(src, dst, bincur, binned);
    k_binB<<<NBINS, 256, 0, stream>>>(binoff, binned, off, esrc);

    // ---- layer 1 (fused agg + dual GEMM) ----
    k_agg_layer1<<<N_NODES / 8, 512, 0, stream>>>(off, esrc, x, w1l, w1r, b1, h1);

    // ---- layer 2 (pre-transform, fused agg + GEMM + classifier) ----
    k_ztrans<<<N_NODES / 8, 256, 0, stream>>>(h1, w2l, z);
    k_agg_layer2_cls<<<N_NODES / 8, 512, 0, stream>>>(off, esrc, z, h1, w2r, b2,
                                                      wc1, bc1, wc2, bc2, out);
}